// Round 1
// baseline (746.262 us; speedup 1.0000x reference)
//
#include <hip/hip_runtime.h>
#include <cstddef>

// Problem constants
#define NB   4
#define CIN  256
#define TT   16
#define HH   28
#define WW   28
#define LL   (TT*HH*WW)      // 12544
#define MIDC 32
#define KCC  128
#define VCC  256
#define HC   8
#define HK   16
#define HV   32
#define SPLIT 8
#define TS   224
#define TSP  225
#define EPSV 1e-5f

// ---------------- pw1: [32x256] @ [256xL] + b, per sample -------------------
// weights staged in LDS transposed to [c][m] so inner reads are float4.
__global__ __launch_bounds__(256) void pw1_kernel(
    const float* __restrict__ in,   // [N][256][L]
    const float* __restrict__ w,    // [32][256]
    const float* __restrict__ b,    // [32]
    float* __restrict__ out)        // [N][32][L]
{
    __shared__ float wl[CIN*MIDC];  // [c][m]
    __shared__ float bl[MIDC];
    const int t = threadIdx.x;
    for (int i = t; i < CIN*MIDC; i += 256) {
        int c = i >> 5, m = i & 31;
        wl[i] = w[m*CIN + c];
    }
    if (t < MIDC) bl[t] = b[t];
    __syncthreads();

    const int n  = blockIdx.y;
    const int l  = blockIdx.x*512 + 2*t;
    if (l >= LL) return;

    float acc0[MIDC], acc1[MIDC];
#pragma unroll
    for (int m = 0; m < MIDC; ++m) { acc0[m] = 0.f; acc1[m] = 0.f; }

    const float* ip = in + (size_t)n*CIN*LL + l;
    for (int c = 0; c < CIN; ++c) {
        float2 x = *reinterpret_cast<const float2*>(ip + (size_t)c*LL);
        const float4* wp = reinterpret_cast<const float4*>(&wl[c*MIDC]);
#pragma unroll
        for (int mq = 0; mq < 8; ++mq) {
            float4 wv = wp[mq];
            acc0[4*mq+0] += wv.x*x.x;  acc1[4*mq+0] += wv.x*x.y;
            acc0[4*mq+1] += wv.y*x.x;  acc1[4*mq+1] += wv.y*x.y;
            acc0[4*mq+2] += wv.z*x.x;  acc1[4*mq+2] += wv.z*x.y;
            acc0[4*mq+3] += wv.w*x.x;  acc1[4*mq+3] += wv.w*x.y;
        }
    }
    float* op = out + (size_t)n*MIDC*LL + l;
#pragma unroll
    for (int m = 0; m < MIDC; ++m) {
        op[(size_t)m*LL]     = acc0[m] + bl[m];
        op[(size_t)m*LL + 1] = acc1[m] + bl[m];
    }
}

// ---------------- depthwise 3x3x3, pad 1 ------------------------------------
__global__ __launch_bounds__(256) void dw_kernel(
    const float* __restrict__ in,   // [N*32][T][H][W]
    const float* __restrict__ w,    // [32][27]
    const float* __restrict__ b,    // [32]
    float* __restrict__ out)
{
    const int nm = blockIdx.y;             // n*32 + m
    const int m  = nm & (MIDC-1);
    const int tz = blockIdx.x;             // t
    __shared__ float wl[27];
    if (threadIdx.x < 27) wl[threadIdx.x] = w[m*27 + threadIdx.x];
    __syncthreads();
    const float bias = b[m];
    const float* ip = in + (size_t)nm*LL;
    float* op = out + (size_t)nm*LL + tz*HH*WW;

    for (int hw = threadIdx.x; hw < HH*WW; hw += 256) {
        const int y = hw / WW, x = hw - y*WW;
        float acc = bias;
#pragma unroll
        for (int dz = 0; dz < 3; ++dz) {
            const int z = tz + dz - 1;
            if (z < 0 || z >= TT) continue;
#pragma unroll
            for (int dy = 0; dy < 3; ++dy) {
                const int yy = y + dy - 1;
                if (yy < 0 || yy >= HH) continue;
#pragma unroll
                for (int dx = 0; dx < 3; ++dx) {
                    const int xx = x + dx - 1;
                    if (xx < 0 || xx >= WW) continue;
                    acc += wl[(dz*3+dy)*3+dx] * ip[((size_t)z*HH + yy)*WW + xx];
                }
            }
        }
        op[hw] = acc;
    }
}

// ---------------- pw2: [OC x 32] @ [32 x L] + b ------------------------------
template<int OC>
__global__ __launch_bounds__(256) void pw2_kernel(
    const float* __restrict__ in,   // [N][32][L]
    const float* __restrict__ w,    // [OC][32]
    const float* __restrict__ b,    // [OC]
    float* __restrict__ out)        // [N][OC][L]
{
    __shared__ float wl[OC*MIDC];
    __shared__ float bl[OC];
    const int t = threadIdx.x;
    for (int i = t; i < OC*MIDC; i += 256) wl[i] = w[i];
    for (int i = t; i < OC; i += 256) bl[i] = b[i];
    __syncthreads();

    const int n = blockIdx.y;
    const int l = blockIdx.x*256 + t;          // L = 49*256 exact
    float r[MIDC];
    const float* ip = in + (size_t)n*MIDC*LL + l;
#pragma unroll
    for (int m = 0; m < MIDC; ++m) r[m] = ip[(size_t)m*LL];

    float* op = out + (size_t)n*OC*LL + l;
    for (int o = 0; o < OC; ++o) {
        const float4* wp = reinterpret_cast<const float4*>(&wl[o*MIDC]);
        float acc = bl[o];
#pragma unroll
        for (int mq = 0; mq < 8; ++mq) {
            float4 wv = wp[mq];
            acc += wv.x*r[4*mq] + wv.y*r[4*mq+1] + wv.z*r[4*mq+2] + wv.w*r[4*mq+3];
        }
        op[(size_t)o*LL] = acc;
    }
}

// ---------------- softmax over L per row (for K) -----------------------------
__global__ __launch_bounds__(256) void softmax_row_kernel(float* __restrict__ x)
{
    float* p = x + (size_t)blockIdx.x*LL;
    const int t = threadIdx.x;
    __shared__ float red[256];

    float mx = -1e30f;
    for (int i = t; i < LL; i += 256) mx = fmaxf(mx, p[i]);
    red[t] = mx; __syncthreads();
    for (int s = 128; s > 0; s >>= 1) { if (t < s) red[t] = fmaxf(red[t], red[t+s]); __syncthreads(); }
    mx = red[0]; __syncthreads();

    float sm = 0.f;
    for (int i = t; i < LL; i += 256) sm += __expf(p[i] - mx);
    red[t] = sm; __syncthreads();
    for (int s = 128; s > 0; s >>= 1) { if (t < s) red[t] += red[t+s]; __syncthreads(); }
    const float inv = 1.f / red[0];

    for (int i = t; i < LL; i += 256) p[i] = __expf(p[i] - mx) * inv;
}

// ---------------- softmax over the 16 per-head channels (for Q) --------------
__global__ __launch_bounds__(256) void softmax_chan_kernel(float* __restrict__ x)
{
    const int nh = blockIdx.y;                 // n*8 + h
    const int n = nh >> 3, h = nh & 7;
    const int l = blockIdx.x*256 + threadIdx.x;
    float* p = x + ((size_t)n*KCC + h*HK)*LL + l;
    float v[HK];
    float mx = -1e30f;
#pragma unroll
    for (int k = 0; k < HK; ++k) { v[k] = p[(size_t)k*LL]; mx = fmaxf(mx, v[k]); }
    float s = 0.f;
#pragma unroll
    for (int k = 0; k < HK; ++k) { v[k] = __expf(v[k] - mx); s += v[k]; }
    const float inv = 1.f / s;
#pragma unroll
    for (int k = 0; k < HK; ++k) p[(size_t)k*LL] = v[k] * inv;
}

// ---------------- context partials: ctx[k][v] += sum_l K[k,l]*V[v,l] ---------
__global__ __launch_bounds__(256) void ctx_partial_kernel(
    const float* __restrict__ Kb, const float* __restrict__ Vb,
    float* __restrict__ ctxp)
{
    const int nh = blockIdx.y;                 // 32
    const int sp = blockIdx.x;                 // SPLIT
    const int n = nh >> 3, h = nh & 7;
    __shared__ float Kt[HK][TSP];
    __shared__ float Vt[HV][TSP];
    const int t = threadIdx.x;
    const int kk = t >> 4;                     // 0..15
    const int v0 = t & 15;
    float acc0 = 0.f, acc1 = 0.f;
    const float* Kp = Kb + ((size_t)n*KCC + h*HK)*LL;
    const float* Vp = Vb + ((size_t)n*VCC + h*HV)*LL;
    const int lbase = sp*(LL/SPLIT);           // 1568 per split = 7 tiles of 224

    for (int tile = 0; tile < (LL/SPLIT)/TS; ++tile) {
        const int l0 = lbase + tile*TS;
        for (int i = t; i < HK*TS; i += 256) { int m = i/TS, j = i - m*TS; Kt[m][j] = Kp[(size_t)m*LL + l0 + j]; }
        for (int i = t; i < HV*TS; i += 256) { int m = i/TS, j = i - m*TS; Vt[m][j] = Vp[(size_t)m*LL + l0 + j]; }
        __syncthreads();
        for (int j = 0; j < TS; ++j) {
            const float kv = Kt[kk][j];
            acc0 += kv * Vt[v0][j];
            acc1 += kv * Vt[v0+16][j];
        }
        __syncthreads();
    }
    float* cp = ctxp + ((size_t)nh*SPLIT + sp)*(HK*HV);
    cp[kk*HV + v0]      = acc0;
    cp[kk*HV + v0 + 16] = acc1;
}

__global__ void ctx_reduce_kernel(const float* __restrict__ ctxp, float* __restrict__ ctx)
{
    const int idx = blockIdx.x*256 + threadIdx.x;   // 16384
    const int nh = idx >> 9;
    const int p  = idx & 511;
    float s = 0.f;
    for (int sp = 0; sp < SPLIT; ++sp) s += ctxp[((size_t)nh*SPLIT + sp)*512 + p];
    ctx[idx] = s;
}

// ---------------- attended: agg[h*32+v][l] = sum_k ctx[k][v] * Q[k][l] -------
__global__ __launch_bounds__(256) void attended_kernel(
    const float* __restrict__ ctx, const float* __restrict__ Qb,
    float* __restrict__ agg)
{
    const int nh = blockIdx.y;
    const int n = nh >> 3, h = nh & 7;
    const int l = blockIdx.x*256 + threadIdx.x;
    __shared__ float cl[HK*HV];
    for (int i = threadIdx.x; i < HK*HV; i += 256) cl[i] = ctx[(size_t)nh*512 + i];
    __syncthreads();

    const float* Qp = Qb + ((size_t)n*KCC + h*HK)*LL + l;
    float q[HK];
#pragma unroll
    for (int k = 0; k < HK; ++k) q[k] = Qp[(size_t)k*LL];

    float* ap = agg + ((size_t)n*VCC + h*HV)*LL + l;
    for (int v = 0; v < HV; ++v) {
        float acc = 0.f;
#pragma unroll
        for (int k = 0; k < HK; ++k) acc += q[k] * cl[k*HV + v];
        ap[(size_t)v*LL] = acc;
    }
}

// ---------------- pw2 of reproj + residual + global-LN partials --------------
__global__ __launch_bounds__(256) void pw2r_kernel(
    const float* __restrict__ in,    // dwr [N][32][L]
    const float* __restrict__ w,     // [256][32]
    const float* __restrict__ b,     // [256]
    const float* __restrict__ resid, // input_ [N][256][L]
    float* __restrict__ xout,        // [N][256][L]
    float* __restrict__ part)        // [2 * N*49]
{
    __shared__ float wl[CIN*MIDC];
    __shared__ float bl[CIN];
    __shared__ float red[256];
    const int t = threadIdx.x;
    for (int i = t; i < CIN*MIDC; i += 256) wl[i] = w[i];
    for (int i = t; i < CIN; i += 256) bl[i] = b[i];
    __syncthreads();

    const int n = blockIdx.y;
    const int l = blockIdx.x*256 + t;
    float r[MIDC];
    const float* ip = in + (size_t)n*MIDC*LL + l;
#pragma unroll
    for (int m = 0; m < MIDC; ++m) r[m] = ip[(size_t)m*LL];

    const float* rp = resid + (size_t)n*CIN*LL + l;
    float* xp = xout + (size_t)n*CIN*LL + l;
    float s1 = 0.f, s2 = 0.f;
    for (int o = 0; o < CIN; ++o) {
        const float4* wp = reinterpret_cast<const float4*>(&wl[o*MIDC]);
        float acc = bl[o];
#pragma unroll
        for (int mq = 0; mq < 8; ++mq) {
            float4 wv = wp[mq];
            acc += wv.x*r[4*mq] + wv.y*r[4*mq+1] + wv.z*r[4*mq+2] + wv.w*r[4*mq+3];
        }
        acc += rp[(size_t)o*LL];
        xp[(size_t)o*LL] = acc;
        s1 += acc; s2 += acc*acc;
    }
    const int bid = blockIdx.y*gridDim.x + blockIdx.x;
    red[t] = s1; __syncthreads();
    for (int s = 128; s > 0; s >>= 1) { if (t < s) red[t] += red[t+s]; __syncthreads(); }
    if (t == 0) part[2*bid] = red[0];
    __syncthreads();
    red[t] = s2; __syncthreads();
    for (int s = 128; s > 0; s >>= 1) { if (t < s) red[t] += red[t+s]; __syncthreads(); }
    if (t == 0) part[2*bid + 1] = red[0];
}

__global__ void stats_kernel(const float* __restrict__ part, int nblocks,
                             float* __restrict__ stats)
{
    __shared__ float r1[256], r2[256];
    const int t = threadIdx.x;
    float s1 = 0.f, s2 = 0.f;
    for (int i = t; i < nblocks; i += 256) { s1 += part[2*i]; s2 += part[2*i+1]; }
    r1[t] = s1; r2[t] = s2; __syncthreads();
    for (int s = 128; s > 0; s >>= 1) { if (t < s) { r1[t] += r1[t+s]; r2[t] += r2[t+s]; } __syncthreads(); }
    if (t == 0) {
        const float M = (float)NB*CIN*LL;
        const float mu = r1[0]/M;
        const float var = r2[0]/M - mu*mu;
        stats[0] = mu;
        stats[1] = 1.0f/sqrtf(var + EPSV);
    }
}

__global__ __launch_bounds__(256) void norm_kernel(
    const float* __restrict__ x, const float* __restrict__ stats,
    float* __restrict__ out)
{
    const float mu = stats[0], inv = stats[1];
    const size_t total = (size_t)NB*CIN*LL;   // divisible by 4
    for (size_t i = ((size_t)blockIdx.x*256 + threadIdx.x)*4; i < total;
         i += (size_t)gridDim.x*256*4) {
        float4 v = *reinterpret_cast<const float4*>(x + i);
        float4 o;
        o.x = (v.x-mu)*inv; o.y = (v.y-mu)*inv; o.z = (v.z-mu)*inv; o.w = (v.w-mu)*inv;
        *reinterpret_cast<float4*>(out + i) = o;
    }
}

// ------------------------------- launcher ------------------------------------
extern "C" void kernel_launch(void* const* d_in, const int* in_sizes, int n_in,
                              void* d_out, int out_size, void* d_ws, size_t ws_size,
                              hipStream_t stream) {
    const float* input   = (const float*)d_in[0];
    const float* k_pw1_w = (const float*)d_in[1];
    const float* k_pw1_b = (const float*)d_in[2];
    const float* k_dw_w  = (const float*)d_in[3];
    const float* k_dw_b  = (const float*)d_in[4];
    const float* k_pw2_w = (const float*)d_in[5];
    const float* k_pw2_b = (const float*)d_in[6];
    const float* q_pw1_w = (const float*)d_in[7];
    const float* q_pw1_b = (const float*)d_in[8];
    const float* q_dw_w  = (const float*)d_in[9];
    const float* q_dw_b  = (const float*)d_in[10];
    const float* q_pw2_w = (const float*)d_in[11];
    const float* q_pw2_b = (const float*)d_in[12];
    const float* v_pw1_w = (const float*)d_in[13];
    const float* v_pw1_b = (const float*)d_in[14];
    const float* v_dw_w  = (const float*)d_in[15];
    const float* v_dw_b  = (const float*)d_in[16];
    const float* v_pw2_w = (const float*)d_in[17];
    const float* v_pw2_b = (const float*)d_in[18];
    const float* r_pw1_w = (const float*)d_in[19];
    const float* r_pw1_b = (const float*)d_in[20];
    const float* r_dw_w  = (const float*)d_in[21];
    const float* r_dw_b  = (const float*)d_in[22];
    const float* r_pw2_w = (const float*)d_in[23];
    const float* r_pw2_b = (const float*)d_in[24];

    float* ws = (float*)d_ws;
    const size_t N32L = (size_t)NB*MIDC*LL;     // 1,605,632
    const size_t NKL  = (size_t)NB*KCC*LL;      // 6,422,528
    const size_t NVL  = (size_t)NB*VCC*LL;      // 12,845,056

    float* midk = ws;
    float* midq = midk + N32L;
    float* midv = midq + N32L;
    float* dk   = ws + 3*N32L;
    float* dq   = dk + N32L;
    float* dv   = dq + N32L;
    float* Kb   = ws + 6*N32L;
    float* Qb   = Kb + NKL;
    float* Vb   = Qb + NKL;
    float* agg  = Vb;                 // reuse: V dead after context
    float* xb   = Kb;                 // reuse: K∪Q dead after attended (spans exactly NVL)
    float* ctxp = Vb + NVL;
    float* ctx  = ctxp + (size_t)NB*HC*SPLIT*HK*HV;
    float* part = ctx + (size_t)NB*HC*HK*HV;
    float* stats= part + 2*49*NB;
    float* midr = midk;
    float* dwr  = dk;

    // k/q/v projections
    pw1_kernel<<<dim3(25, NB), 256, 0, stream>>>(input, k_pw1_w, k_pw1_b, midk);
    pw1_kernel<<<dim3(25, NB), 256, 0, stream>>>(input, q_pw1_w, q_pw1_b, midq);
    pw1_kernel<<<dim3(25, NB), 256, 0, stream>>>(input, v_pw1_w, v_pw1_b, midv);
    dw_kernel<<<dim3(TT, NB*MIDC), 256, 0, stream>>>(midk, k_dw_w, k_dw_b, dk);
    dw_kernel<<<dim3(TT, NB*MIDC), 256, 0, stream>>>(midq, q_dw_w, q_dw_b, dq);
    dw_kernel<<<dim3(TT, NB*MIDC), 256, 0, stream>>>(midv, v_dw_w, v_dw_b, dv);
    pw2_kernel<KCC><<<dim3(49, NB), 256, 0, stream>>>(dk, k_pw2_w, k_pw2_b, Kb);
    pw2_kernel<KCC><<<dim3(49, NB), 256, 0, stream>>>(dq, q_pw2_w, q_pw2_b, Qb);
    pw2_kernel<VCC><<<dim3(49, NB), 256, 0, stream>>>(dv, v_pw2_w, v_pw2_b, Vb);

    // attention
    softmax_row_kernel<<<NB*KCC, 256, 0, stream>>>(Kb);
    softmax_chan_kernel<<<dim3(49, NB*HC), 256, 0, stream>>>(Qb);
    ctx_partial_kernel<<<dim3(SPLIT, NB*HC), 256, 0, stream>>>(Kb, Vb, ctxp);
    ctx_reduce_kernel<<<64, 256, 0, stream>>>(ctxp, ctx);
    attended_kernel<<<dim3(49, NB*HC), 256, 0, stream>>>(ctx, Qb, agg);

    // reprojection + residual + global layernorm
    pw1_kernel<<<dim3(25, NB), 256, 0, stream>>>(agg, r_pw1_w, r_pw1_b, midr);
    dw_kernel<<<dim3(TT, NB*MIDC), 256, 0, stream>>>(midr, r_dw_w, r_dw_b, dwr);
    pw2r_kernel<<<dim3(49, NB), 256, 0, stream>>>(dwr, r_pw2_w, r_pw2_b, input, xb, part);
    stats_kernel<<<1, 256, 0, stream>>>(part, 49*NB, stats);
    norm_kernel<<<2048, 256, 0, stream>>>(xb, stats, (float*)d_out);
}

// Round 2
// 376.496 us; speedup vs baseline: 1.9821x; 1.9821x over previous
//
#include <hip/hip_runtime.h>
#include <cstddef>

// Problem constants
#define NB   4
#define CIN  256
#define TT   16
#define HH   28
#define WW   28
#define LL   (TT*HH*WW)      // 12544 = 49*256
#define MIDC 32
#define KCC  128
#define VCC  256
#define HC   8
#define HK   16
#define HV   32
#define CTXSPLIT 49
#define EPSV 1e-5f

struct TripC { const float* p[3]; };
struct TripO { float* p[3]; };
struct DwA   { const float* in[3]; const float* w[3]; const float* b[3]; float* out[3]; };
struct Pw2A  { const float* in[3]; const float* w[3]; const float* b[3]; float* out[3]; int ocn[3]; };

// ---------------- pw1 fused (k,q,v): [32x256] @ [256xL] + b ------------------
// blockIdx.z selects the weight set. 1 l per thread -> grid (49, NB, 3).
__global__ __launch_bounds__(256) void pw1_fused(
    const float* __restrict__ in, TripC w, TripC bia, TripO out)
{
    const int z = blockIdx.z;
    const float* wz = w.p[z];
    __shared__ float wl[CIN*MIDC];  // [c][m]
    const int t = threadIdx.x;
    for (int i = t; i < CIN*MIDC; i += 256) { int c = i >> 5, m = i & 31; wl[i] = wz[m*CIN + c]; }
    __syncthreads();

    const int n = blockIdx.y;
    const int l = blockIdx.x*256 + t;
    float acc[MIDC];
#pragma unroll
    for (int m = 0; m < MIDC; ++m) acc[m] = 0.f;

    const float* ip = in + (size_t)n*CIN*LL + l;
#pragma unroll 4
    for (int c = 0; c < CIN; ++c) {
        float x = ip[(size_t)c*LL];
        const float4* wp = reinterpret_cast<const float4*>(&wl[c*MIDC]);
#pragma unroll
        for (int mq = 0; mq < 8; ++mq) {
            float4 wv = wp[mq];
            acc[4*mq+0] += wv.x*x; acc[4*mq+1] += wv.y*x;
            acc[4*mq+2] += wv.z*x; acc[4*mq+3] += wv.w*x;
        }
    }
    const float* bz = bia.p[z];
    float* op = out.p[z] + (size_t)n*MIDC*LL + l;
#pragma unroll
    for (int m = 0; m < MIDC; ++m) op[(size_t)m*LL] = acc[m] + bz[m];
}

// ---------------- pw1 for reprojection, split over 16-channel halves --------
__global__ __launch_bounds__(256) void pw1_half(
    const float* __restrict__ in, const float* __restrict__ w,
    const float* __restrict__ bia, float* __restrict__ out)
{
    const int mz = blockIdx.z;          // 0..1
    __shared__ float wl[CIN*16];        // [c][mm]
    const int t = threadIdx.x;
    for (int i = t; i < CIN*16; i += 256) { int c = i >> 4, mm = i & 15; wl[i] = w[(size_t)(mz*16+mm)*CIN + c]; }
    __syncthreads();

    const int n = blockIdx.y;
    const int l = blockIdx.x*256 + t;
    float acc[16];
#pragma unroll
    for (int m = 0; m < 16; ++m) acc[m] = 0.f;

    const float* ip = in + (size_t)n*CIN*LL + l;
#pragma unroll 4
    for (int c = 0; c < CIN; ++c) {
        float x = ip[(size_t)c*LL];
        const float4* wp = reinterpret_cast<const float4*>(&wl[c*16]);
#pragma unroll
        for (int mq = 0; mq < 4; ++mq) {
            float4 wv = wp[mq];
            acc[4*mq+0] += wv.x*x; acc[4*mq+1] += wv.y*x;
            acc[4*mq+2] += wv.z*x; acc[4*mq+3] += wv.w*x;
        }
    }
    float* op = out + ((size_t)n*MIDC + mz*16)*LL + l;
#pragma unroll
    for (int m = 0; m < 16; ++m) op[(size_t)m*LL] = acc[m] + bia[mz*16+m];
}

// ---------------- depthwise 3x3x3, pad 1, z selects set ---------------------
__global__ __launch_bounds__(256) void dw_fused(DwA a)
{
    const int z  = blockIdx.z;
    const int nm = blockIdx.y;             // n*32 + m
    const int m  = nm & (MIDC-1);
    const int tz = blockIdx.x;             // t
    __shared__ float wl[27];
    if (threadIdx.x < 27) wl[threadIdx.x] = a.w[z][m*27 + threadIdx.x];
    __syncthreads();
    const float bias = a.b[z][m];
    const float* ip = a.in[z] + (size_t)nm*LL;
    float* op = a.out[z] + (size_t)nm*LL + tz*HH*WW;

    for (int hw = threadIdx.x; hw < HH*WW; hw += 256) {
        const int y = hw / WW, x = hw - y*WW;
        float acc = bias;
#pragma unroll
        for (int dz = 0; dz < 3; ++dz) {
            const int zz = tz + dz - 1;
            if (zz < 0 || zz >= TT) continue;
#pragma unroll
            for (int dy = 0; dy < 3; ++dy) {
                const int yy = y + dy - 1;
                if (yy < 0 || yy >= HH) continue;
#pragma unroll
                for (int dx = 0; dx < 3; ++dx) {
                    const int xx = x + dx - 1;
                    if (xx < 0 || xx >= WW) continue;
                    acc += wl[(dz*3+dy)*3+dx] * ip[((size_t)zz*HH + yy)*WW + xx];
                }
            }
        }
        op[hw] = acc;
    }
}

// ---------------- pw2 fused (k,q,v) with 64-channel output chunks ------------
// z: 0-1 -> k chunks, 2-3 -> q chunks, 4-7 -> v chunks. grid (49, NB, 8).
__global__ __launch_bounds__(256) void pw2_fused(Pw2A a)
{
    const int z = blockIdx.z;
    int set, oz;
    if (z < 2)      { set = 0; oz = z; }
    else if (z < 4) { set = 1; oz = z - 2; }
    else            { set = 2; oz = z - 4; }

    __shared__ float wl[64*MIDC];
    __shared__ float bl[64];
    const int t = threadIdx.x;
    const float* wz = a.w[set] + (size_t)oz*64*MIDC;
    for (int i = t; i < 64*MIDC; i += 256) wl[i] = wz[i];
    if (t < 64) bl[t] = a.b[set][oz*64 + t];
    __syncthreads();

    const int n = blockIdx.y;
    const int l = blockIdx.x*256 + t;
    float r[MIDC];
    const float* ip = a.in[set] + (size_t)n*MIDC*LL + l;
#pragma unroll
    for (int m = 0; m < MIDC; ++m) r[m] = ip[(size_t)m*LL];

    const int OC = a.ocn[set];
    float* op = a.out[set] + ((size_t)n*OC + oz*64)*LL + l;
    for (int o = 0; o < 64; ++o) {
        const float4* wp = reinterpret_cast<const float4*>(&wl[o*MIDC]);
        float acc = bl[o];
#pragma unroll
        for (int mq = 0; mq < 8; ++mq) {
            float4 wv = wp[mq];
            acc += wv.x*r[4*mq] + wv.y*r[4*mq+1] + wv.z*r[4*mq+2] + wv.w*r[4*mq+3];
        }
        op[(size_t)o*LL] = acc;
    }
}

// ---------------- K row softmax stats: max and 1/sum(exp) --------------------
__global__ __launch_bounds__(256) void krowstats(const float* __restrict__ K, float* __restrict__ st)
{
    const float* p = K + (size_t)blockIdx.x*LL;
    const int t = threadIdx.x;
    __shared__ float red[256];
    float mx = -1e30f;
    for (int i = t; i < LL; i += 256) mx = fmaxf(mx, p[i]);
    red[t] = mx; __syncthreads();
    for (int s = 128; s > 0; s >>= 1) { if (t < s) red[t] = fmaxf(red[t], red[t+s]); __syncthreads(); }
    mx = red[0]; __syncthreads();
    float sm = 0.f;
    for (int i = t; i < LL; i += 256) sm += __expf(p[i] - mx);
    red[t] = sm; __syncthreads();
    for (int s = 128; s > 0; s >>= 1) { if (t < s) red[t] += red[t+s]; __syncthreads(); }
    if (t == 0) { st[2*blockIdx.x] = mx; st[2*blockIdx.x+1] = 1.f/red[0]; }
}

// ---------------- context partials over 49 L-tiles of 256 --------------------
__global__ __launch_bounds__(256) void ctx_partial(
    const float* __restrict__ Kb, const float* __restrict__ Vb,
    const float* __restrict__ st, float* __restrict__ ctxp)
{
    const int nh = blockIdx.y;                 // 32
    const int sp = blockIdx.x;                 // 49
    const int n = nh >> 3, h = nh & 7;
    __shared__ float Kt[HK][257];
    __shared__ float Vt[HV][257];
    __shared__ float mxs[HK], invs[HK];
    const int t = threadIdx.x;
    const int rowbase = n*KCC + h*HK;
    if (t < HK) { mxs[t] = st[2*(rowbase+t)]; invs[t] = st[2*(rowbase+t)+1]; }
    __syncthreads();

    const int l0 = sp*256;
    const float* Kp = Kb + (size_t)rowbase*LL + l0;
    const float* Vp = Vb + ((size_t)n*VCC + h*HV)*LL + l0;
#pragma unroll
    for (int m = 0; m < HK; ++m) Kt[m][t] = __expf(Kp[(size_t)m*LL + t] - mxs[m]) * invs[m];
#pragma unroll
    for (int m = 0; m < HV; ++m) Vt[m][t] = Vp[(size_t)m*LL + t];
    __syncthreads();

    const int kk = t >> 4, v0 = t & 15;
    float acc0 = 0.f, acc1 = 0.f;
    for (int j = 0; j < 256; ++j) {
        const float kv = Kt[kk][j];
        acc0 += kv * Vt[v0][j];
        acc1 += kv * Vt[v0+16][j];
    }
    float* cp = ctxp + ((size_t)nh*CTXSPLIT + sp)*(HK*HV);
    cp[kk*HV + v0]      = acc0;
    cp[kk*HV + v0 + 16] = acc1;
}

__global__ void ctx_reduce(const float* __restrict__ ctxp, float* __restrict__ ctx)
{
    const int idx = blockIdx.x*256 + threadIdx.x;   // 16384
    const int nh = idx >> 9;
    const int p  = idx & 511;
    float s = 0.f;
    for (int sp = 0; sp < CTXSPLIT; ++sp) s += ctxp[((size_t)nh*CTXSPLIT + sp)*512 + p];
    ctx[idx] = s;
}

// ------- attended with fused Q channel-softmax: agg = ctx^T @ softmax(Q) -----
__global__ __launch_bounds__(256) void attended_kernel(
    const float* __restrict__ ctx, const float* __restrict__ Qb,
    float* __restrict__ agg)
{
    const int nh = blockIdx.y;
    const int n = nh >> 3, h = nh & 7;
    const int l = blockIdx.x*256 + threadIdx.x;
    __shared__ float cl[HK*HV];
    for (int i = threadIdx.x; i < HK*HV; i += 256) cl[i] = ctx[(size_t)nh*512 + i];
    __syncthreads();

    const float* Qp = Qb + ((size_t)n*KCC + h*HK)*LL + l;
    float q[HK];
    float mx = -1e30f;
#pragma unroll
    for (int k = 0; k < HK; ++k) { q[k] = Qp[(size_t)k*LL]; mx = fmaxf(mx, q[k]); }
    float s = 0.f;
#pragma unroll
    for (int k = 0; k < HK; ++k) { q[k] = __expf(q[k] - mx); s += q[k]; }
    const float inv = 1.f / s;
#pragma unroll
    for (int k = 0; k < HK; ++k) q[k] *= inv;

    float* ap = agg + ((size_t)n*VCC + h*HV)*LL + l;
#pragma unroll 4
    for (int v = 0; v < HV; ++v) {
        float acc = 0.f;
#pragma unroll
        for (int k = 0; k < HK; ++k) acc += q[k] * cl[k*HV + v];
        ap[(size_t)v*LL] = acc;
    }
}

// ------- pw2 of reproj + residual + global-LN partials, 64-chan chunks -------
__global__ __launch_bounds__(256) void pw2r_kernel(
    const float* __restrict__ in,    // dwr [N][32][L]
    const float* __restrict__ w,     // [256][32]
    const float* __restrict__ b,     // [256]
    const float* __restrict__ resid, // input_ [N][256][L]
    float* __restrict__ xout,        // [N][256][L]
    float* __restrict__ part)        // [2 * 784]
{
    const int oz = blockIdx.z;       // 0..3
    __shared__ float wl[64*MIDC];
    __shared__ float bl[64];
    __shared__ float red[256];
    const int t = threadIdx.x;
    const float* wz = w + (size_t)oz*64*MIDC;
    for (int i = t; i < 64*MIDC; i += 256) wl[i] = wz[i];
    if (t < 64) bl[t] = b[oz*64 + t];
    __syncthreads();

    const int n = blockIdx.y;
    const int l = blockIdx.x*256 + t;
    float r[MIDC];
    const float* ip = in + (size_t)n*MIDC*LL + l;
#pragma unroll
    for (int m = 0; m < MIDC; ++m) r[m] = ip[(size_t)m*LL];

    const float* rp = resid + ((size_t)n*CIN + oz*64)*LL + l;
    float* xp = xout + ((size_t)n*CIN + oz*64)*LL + l;
    float s1 = 0.f, s2 = 0.f;
    for (int o = 0; o < 64; ++o) {
        const float4* wp = reinterpret_cast<const float4*>(&wl[o*MIDC]);
        float acc = bl[o];
#pragma unroll
        for (int mq = 0; mq < 8; ++mq) {
            float4 wv = wp[mq];
            acc += wv.x*r[4*mq] + wv.y*r[4*mq+1] + wv.z*r[4*mq+2] + wv.w*r[4*mq+3];
        }
        acc += rp[(size_t)o*LL];
        xp[(size_t)o*LL] = acc;
        s1 += acc; s2 += acc*acc;
    }
    const int bid = (blockIdx.y*gridDim.x + blockIdx.x)*4 + oz;   // 0..783
    red[t] = s1; __syncthreads();
    for (int s = 128; s > 0; s >>= 1) { if (t < s) red[t] += red[t+s]; __syncthreads(); }
    if (t == 0) part[2*bid] = red[0];
    __syncthreads();
    red[t] = s2; __syncthreads();
    for (int s = 128; s > 0; s >>= 1) { if (t < s) red[t] += red[t+s]; __syncthreads(); }
    if (t == 0) part[2*bid + 1] = red[0];
}

__global__ void stats_kernel(const float* __restrict__ part, int nblocks,
                             float* __restrict__ stats)
{
    __shared__ float r1[256], r2[256];
    const int t = threadIdx.x;
    float s1 = 0.f, s2 = 0.f;
    for (int i = t; i < nblocks; i += 256) { s1 += part[2*i]; s2 += part[2*i+1]; }
    r1[t] = s1; r2[t] = s2; __syncthreads();
    for (int s = 128; s > 0; s >>= 1) { if (t < s) { r1[t] += r1[t+s]; r2[t] += r2[t+s]; } __syncthreads(); }
    if (t == 0) {
        const float M = (float)NB*CIN*LL;
        const float mu = r1[0]/M;
        const float var = r2[0]/M - mu*mu;
        stats[0] = mu;
        stats[1] = 1.0f/sqrtf(var + EPSV);
    }
}

__global__ __launch_bounds__(256) void norm_kernel(
    const float* __restrict__ x, const float* __restrict__ stats,
    float* __restrict__ out)
{
    const float mu = stats[0], inv = stats[1];
    const size_t total = (size_t)NB*CIN*LL;   // divisible by 4
    for (size_t i = ((size_t)blockIdx.x*256 + threadIdx.x)*4; i < total;
         i += (size_t)gridDim.x*256*4) {
        float4 v = *reinterpret_cast<const float4*>(x + i);
        float4 o;
        o.x = (v.x-mu)*inv; o.y = (v.y-mu)*inv; o.z = (v.z-mu)*inv; o.w = (v.w-mu)*inv;
        *reinterpret_cast<float4*>(out + i) = o;
    }
}

// ------------------------------- launcher ------------------------------------
extern "C" void kernel_launch(void* const* d_in, const int* in_sizes, int n_in,
                              void* d_out, int out_size, void* d_ws, size_t ws_size,
                              hipStream_t stream) {
    const float* input   = (const float*)d_in[0];
    const float* k_pw1_w = (const float*)d_in[1];
    const float* k_pw1_b = (const float*)d_in[2];
    const float* k_dw_w  = (const float*)d_in[3];
    const float* k_dw_b  = (const float*)d_in[4];
    const float* k_pw2_w = (const float*)d_in[5];
    const float* k_pw2_b = (const float*)d_in[6];
    const float* q_pw1_w = (const float*)d_in[7];
    const float* q_pw1_b = (const float*)d_in[8];
    const float* q_dw_w  = (const float*)d_in[9];
    const float* q_dw_b  = (const float*)d_in[10];
    const float* q_pw2_w = (const float*)d_in[11];
    const float* q_pw2_b = (const float*)d_in[12];
    const float* v_pw1_w = (const float*)d_in[13];
    const float* v_pw1_b = (const float*)d_in[14];
    const float* v_dw_w  = (const float*)d_in[15];
    const float* v_dw_b  = (const float*)d_in[16];
    const float* v_pw2_w = (const float*)d_in[17];
    const float* v_pw2_b = (const float*)d_in[18];
    const float* r_pw1_w = (const float*)d_in[19];
    const float* r_pw1_b = (const float*)d_in[20];
    const float* r_dw_w  = (const float*)d_in[21];
    const float* r_dw_b  = (const float*)d_in[22];
    const float* r_pw2_w = (const float*)d_in[23];
    const float* r_pw2_b = (const float*)d_in[24];

    float* ws = (float*)d_ws;
    const size_t N32L = (size_t)NB*MIDC*LL;     // 1,605,632
    const size_t NKL  = (size_t)NB*KCC*LL;      // 6,422,528
    const size_t NVL  = (size_t)NB*VCC*LL;      // 12,845,056

    float* midk = ws;
    float* midq = midk + N32L;
    float* midv = midq + N32L;
    float* dk   = ws + 3*N32L;
    float* dq   = dk + N32L;
    float* dv   = dq + N32L;
    float* Kb   = ws + 6*N32L;
    float* Qb   = Kb + NKL;
    float* Vb   = Qb + NKL;
    float* agg  = Vb;          // V dead after ctx_partial
    float* xb   = Kb;          // K,Q dead after attended; spans exactly NVL
    // regions reused after their producers are consumed:
    float* ctxp = dk;          // 802,816 floats <= N32L; dk/dq/dv dead after pw2_fused
    float* ctx  = dv;          // 16,384 floats
    float* kst  = dv + 20000;  // 1,024 floats
    float* part = dv + 24000;  // 1,568 floats
    float* statsp = dv + 28000;
    float* midr = midk;        // mids dead after dw_fused
    float* dwr  = dk;          // ctxp dead after ctx_reduce

    // k/q/v projections
    {
        TripC w  = {{k_pw1_w, q_pw1_w, v_pw1_w}};
        TripC bi = {{k_pw1_b, q_pw1_b, v_pw1_b}};
        TripO o  = {{midk, midq, midv}};
        pw1_fused<<<dim3(49, NB, 3), 256, 0, stream>>>(input, w, bi, o);
    }
    {
        DwA a;
        a.in[0]=midk; a.in[1]=midq; a.in[2]=midv;
        a.w[0]=k_dw_w; a.w[1]=q_dw_w; a.w[2]=v_dw_w;
        a.b[0]=k_dw_b; a.b[1]=q_dw_b; a.b[2]=v_dw_b;
        a.out[0]=dk; a.out[1]=dq; a.out[2]=dv;
        dw_fused<<<dim3(TT, NB*MIDC, 3), 256, 0, stream>>>(a);
    }
    {
        Pw2A a;
        a.in[0]=dk; a.in[1]=dq; a.in[2]=dv;
        a.w[0]=k_pw2_w; a.w[1]=q_pw2_w; a.w[2]=v_pw2_w;
        a.b[0]=k_pw2_b; a.b[1]=q_pw2_b; a.b[2]=v_pw2_b;
        a.out[0]=Kb; a.out[1]=Qb; a.out[2]=Vb;
        a.ocn[0]=KCC; a.ocn[1]=KCC; a.ocn[2]=VCC;
        pw2_fused<<<dim3(49, NB, 8), 256, 0, stream>>>(a);
    }

    // attention
    krowstats<<<NB*KCC, 256, 0, stream>>>(Kb, kst);
    ctx_partial<<<dim3(CTXSPLIT, NB*HC), 256, 0, stream>>>(Kb, Vb, kst, ctxp);
    ctx_reduce<<<64, 256, 0, stream>>>(ctxp, ctx);
    attended_kernel<<<dim3(49, NB*HC), 256, 0, stream>>>(ctx, Qb, agg);

    // reprojection + residual + global layernorm
    pw1_half<<<dim3(49, NB, 2), 256, 0, stream>>>(agg, r_pw1_w, r_pw1_b, midr);
    {
        DwA a;
        a.in[0]=midr; a.w[0]=r_dw_w; a.b[0]=r_dw_b; a.out[0]=dwr;
        a.in[1]=midr; a.w[1]=r_dw_w; a.b[1]=r_dw_b; a.out[1]=dwr;
        a.in[2]=midr; a.w[2]=r_dw_w; a.b[2]=r_dw_b; a.out[2]=dwr;
        dw_fused<<<dim3(TT, NB*MIDC, 1), 256, 0, stream>>>(a);
    }
    pw2r_kernel<<<dim3(49, NB, 4), 256, 0, stream>>>(dwr, r_pw2_w, r_pw2_b, input, xb, part);
    stats_kernel<<<1, 256, 0, stream>>>(part, 4*49*NB, statsp);
    norm_kernel<<<2048, 256, 0, stream>>>(xb, statsp, (float*)d_out);
}